// Round 8
// baseline (104.713 us; speedup 1.0000x reference)
//
#include <hip/hip_runtime.h>
#include <hip/hip_fp16.h>

// Problem constants: L=4, DIM=17, S=4, B=4, H=256, W=256, BINSIZE=16
#define HH   256
#define WW   256
#define HWPX (HH * WW)           // 65536
#define DD   17
#define D4   (17 * 17 * 17 * 17) // 83521
#define NL   4
#define SS   16                  // S*S
#define LUT_FLOATS  (NL * D4 * SS)            // 5,345,344 floats
#define LUT_BYTES_H ((size_t)LUT_FLOATS * 2)  // ~10.7 MB (fp16 transposed copy)

// Touch window: 896 chunks x 4KB = 3.5 MiB (< 4 MiB L2/XCD), replicated 8x
// so every XCD pulls the same window into its L2 as CLEAN lines.
#define TOUCH_CHUNKS 896
#define TOUCH_STRIDE 897          // 897 % 8 == 1 -> (c + s*897) % 8 covers all XCDs

// ---------------------------------------------------------------------------
// Kernel 1: transpose + fp16-convert LUT (L, D4, 16) f32 -> (D4, L, 16) f16.
// One vertex's four l-rows become exactly ONE 128B cache line.
// ---------------------------------------------------------------------------
__global__ __launch_bounds__(256) void lut_transpose_h_kernel(
    const float4* __restrict__ src,   // (L, D4, 4) float4
    ushort* __restrict__ dst)         // (D4, L, 16) halfs as ushort
{
    int t = blockIdx.x * blockDim.x + threadIdx.x;  // 4-half chunk index in dst
    if (t >= D4 * NL * 4) return;
    int c4 = t & 3;
    int l  = (t >> 2) & 3;
    int v  = t >> 4;
    float4 r = src[(size_t)l * (D4 * 4) + (size_t)v * 4 + c4];
    ushort4 h;
    h.x = __half_as_ushort(__float2half_rn(r.x));
    h.y = __half_as_ushort(__float2half_rn(r.y));
    h.z = __half_as_ushort(__float2half_rn(r.z));
    h.w = __half_as_ushort(__float2half_rn(r.w));
    *((ushort4*)(dst + (size_t)t * 4)) = h;   // coalesced 8B stores
}

// ---------------------------------------------------------------------------
// Kernel 1.5: L2 prewarm. Block b touches chunk (b % TOUCH_STRIDE) of the
// 3.5 MiB lutT window; the 8 replicas of each chunk land on all 8 XCDs
// (blockIdx -> XCD is round-robin %8 and 897 is coprime to 8). Leaves each
// XCD's L2 holding the window as CLEAN lines (round-4 measured: clean lines
// survive kernel boundaries; warm main ran 2.2x faster). Reads only.
// ---------------------------------------------------------------------------
__global__ __launch_bounds__(256) void lut_touch_kernel(
    const uint4* __restrict__ lutT4)
{
    int c = blockIdx.x % TOUCH_STRIDE;
    if (c >= TOUCH_CHUNKS) return;
    uint4 v = lutT4[(size_t)c * 256 + threadIdx.x];   // 4KB per chunk, coalesced
    // keep the load alive without any memory side effect (rule #17)
    asm volatile("" :: "v"(v.x), "v"(v.y), "v"(v.z), "v"(v.w));
}

// ---------------------------------------------------------------------------
// Kernel 2: main interpolation (round-3 structure). 8 lanes per pixel;
// lane j does ONE dwordx4 (16B) load per vertex at flat*128 + j*16 -> the
// 8 lanes tile the whole 128B vertex line in a single instruction.
// 5 line-lookups per pixel; butterfly shfl_xor reduce over the 4 l-lanes.
// ---------------------------------------------------------------------------
__global__ __launch_bounds__(256) void lut4d_kernel_v(
    const ushort* __restrict__ lutT,   // (D4, L, 16) fp16
    const float* __restrict__ weight,  // (B, L, H, W)
    const float* __restrict__ x,       // (B, 1, H, W)
    float* __restrict__ out)           // (B, 1, H*4, W*4)
{
    int tid = blockIdx.x * blockDim.x + threadIdx.x;  // [0, 8*B*H*W)
    int j = tid & 7;          // sub-pixel lane: l = j>>1, half = j&1
    int p = tid >> 3;         // pixel id
    int b  = p >> 16;
    int hw = p & 65535;
    int h  = hw >> 8;
    int w  = hw & 255;
    int l  = j >> 1;

    const float* xb = x + b * HWPX;
    int h1 = (h + 1 < HH) ? (h + 1) : (HH - 2);   // reflect pad
    int w1 = (w + 1 < WW) ? (w + 1) : (WW - 2);

    float pix0 = xb[h  * WW + w ];
    float pix1 = xb[h  * WW + w1];
    float pix2 = xb[h1 * WW + w ];
    float pix3 = xb[h1 * WW + w1];

    // this lane's lut weight (only l = j>>1 needed per lane)
    float wlv = weight[(size_t)b * (NL * HWPX) + (size_t)l * HWPX + hw];

    const float inv = 1.0f / 16.0f;
    float t0 = pix0 * inv, t1 = pix1 * inv, t2 = pix2 * inv, t3 = pix3 * inv;
    float bf0 = floorf(t0), bf1 = floorf(t1), bf2 = floorf(t2), bf3 = floorf(t3);
    float f0 = t0 - bf0, f1 = t1 - bf1, f2 = t2 - bf2, f3 = t3 - bf3;

    int b0 = min(max((int)bf0, 0), DD - 2);
    int b1 = min(max((int)bf1, 0), DD - 2);
    int b2 = min(max((int)bf2, 0), DD - 2);
    int b3 = min(max((int)bf3, 0), DD - 2);

    // Stable descending sort of (frac, stride); strides strictly decrease
    // with original index so tie-break by larger stride == stable argsort.
    float s0f = f0, s1f = f1, s2f = f2, s3f = f3;
    int   s0s = 4913, s1s = 289, s2s = 17, s3s = 1;

#define CSWAP(fa, sa, fb, sb)                                          \
    do {                                                               \
        bool sw = (fb > fa) || ((fb == fa) && (sb > sa));              \
        float tf = fa; int ts = sa;                                    \
        if (sw) { fa = fb; sa = sb; fb = tf; sb = ts; }                \
    } while (0)

    CSWAP(s0f, s0s, s1f, s1s);
    CSWAP(s2f, s2s, s3f, s3s);
    CSWAP(s0f, s0s, s2f, s2s);
    CSWAP(s1f, s1s, s3f, s3s);
    CSWAP(s1f, s1s, s2f, s2s);
#undef CSWAP

    float wts[5];
    wts[0] = 1.0f - s0f;
    wts[1] = s0f - s1f;
    wts[2] = s1f - s2f;
    wts[3] = s2f - s3f;
    wts[4] = s3f;

    int flats[5];
    flats[0] = ((b0 * DD + b1) * DD + b2) * DD + b3;
    flats[1] = flats[0] + s0s;
    flats[2] = flats[1] + s1s;
    flats[3] = flats[2] + s2s;
    flats[4] = flats[3] + s3s;

    // Issue all 5 independent 16B gathers: lane j covers bytes [j*16, j*16+16)
    // of the 128B vertex line -> one fully-coalesced line fetch per vertex.
    uint4 r[5];
#pragma unroll
    for (int k = 0; k < 5; ++k) {
        const ushort* vbase = lutT + (size_t)flats[k] * (NL * SS);
        r[k] = *((const uint4*)(vbase) + j);
    }

    // Lane j holds lut[l = j>>1][channels (j&1)*8 .. +7] for each vertex.
    float acc0 = 0.f, acc1 = 0.f, acc2 = 0.f, acc3 = 0.f;
    float acc4 = 0.f, acc5 = 0.f, acc6 = 0.f, acc7 = 0.f;
#pragma unroll
    for (int k = 0; k < 5; ++k) {
        float c = wlv * wts[k];
        float2 f0v = __half22float2(*reinterpret_cast<const __half2*>(&r[k].x));
        float2 f1v = __half22float2(*reinterpret_cast<const __half2*>(&r[k].y));
        float2 f2v = __half22float2(*reinterpret_cast<const __half2*>(&r[k].z));
        float2 f3v = __half22float2(*reinterpret_cast<const __half2*>(&r[k].w));
        acc0 = fmaf(c, f0v.x, acc0);
        acc1 = fmaf(c, f0v.y, acc1);
        acc2 = fmaf(c, f1v.x, acc2);
        acc3 = fmaf(c, f1v.y, acc3);
        acc4 = fmaf(c, f2v.x, acc4);
        acc5 = fmaf(c, f2v.y, acc5);
        acc6 = fmaf(c, f3v.x, acc6);
        acc7 = fmaf(c, f3v.y, acc7);
    }

    // Butterfly-sum across the 4 l-lanes (same j&1): masks 2 then 4.
#define RED(mask)                                                      \
    do {                                                               \
        acc0 += __shfl_xor(acc0, mask, 64);                            \
        acc1 += __shfl_xor(acc1, mask, 64);                            \
        acc2 += __shfl_xor(acc2, mask, 64);                            \
        acc3 += __shfl_xor(acc3, mask, 64);                            \
        acc4 += __shfl_xor(acc4, mask, 64);                            \
        acc5 += __shfl_xor(acc5, mask, 64);                            \
        acc6 += __shfl_xor(acc6, mask, 64);                            \
        acc7 += __shfl_xor(acc7, mask, 64);                            \
    } while (0)
    RED(2);
    RED(4);
#undef RED

    // All 4 l-lanes now hold identical sums for channels (j&1)*8 .. +7.
    // Lane j writes global channels c0 = (j&1)*8 + (j>>1)*2, c0+1.
    int sel = j >> 1;
    float o0 = (sel == 0) ? acc0 : (sel == 1) ? acc2 : (sel == 2) ? acc4 : acc6;
    float o1 = (sel == 0) ? acc1 : (sel == 1) ? acc3 : (sel == 2) ? acc5 : acc7;

    int c0  = (j & 1) * 8 + sel * 2;
    int row = c0 >> 2;        // s-row
    int col = c0 & 3;         // s-col
    float* ob = out + (size_t)b * (HH * 4) * (WW * 4)
                    + (size_t)(h * 4 + row) * (WW * 4)
                    + (w * 4) + col;
    *((float2*)ob) = make_float2(o0, o1);
}

// ---------------------------------------------------------------------------
// Fallback (no workspace): original layout, fp32.
// ---------------------------------------------------------------------------
__global__ __launch_bounds__(256) void lut4d_kernel_fallback(
    const float* __restrict__ lut,
    const float* __restrict__ weight,
    const float* __restrict__ x,
    float* __restrict__ out)
{
    int p = blockIdx.x * blockDim.x + threadIdx.x;
    int b  = p >> 16;
    int hw = p & 65535;
    int h  = hw >> 8;
    int w  = hw & 255;

    const float* xb = x + b * HWPX;
    int h1 = (h + 1 < HH) ? (h + 1) : (HH - 2);
    int w1 = (w + 1 < WW) ? (w + 1) : (WW - 2);

    float pix0 = xb[h  * WW + w ];
    float pix1 = xb[h  * WW + w1];
    float pix2 = xb[h1 * WW + w ];
    float pix3 = xb[h1 * WW + w1];

    const float inv = 1.0f / 16.0f;
    float t0 = pix0 * inv, t1 = pix1 * inv, t2 = pix2 * inv, t3 = pix3 * inv;
    float bf0 = floorf(t0), bf1 = floorf(t1), bf2 = floorf(t2), bf3 = floorf(t3);
    float f0 = t0 - bf0, f1 = t1 - bf1, f2 = t2 - bf2, f3 = t3 - bf3;

    int b0 = min(max((int)bf0, 0), DD - 2);
    int b1 = min(max((int)bf1, 0), DD - 2);
    int b2 = min(max((int)bf2, 0), DD - 2);
    int b3 = min(max((int)bf3, 0), DD - 2);

    float s0f = f0, s1f = f1, s2f = f2, s3f = f3;
    int   s0s = 4913, s1s = 289, s2s = 17, s3s = 1;

#define CSWAP(fa, sa, fb, sb)                                          \
    do {                                                               \
        bool sw = (fb > fa) || ((fb == fa) && (sb > sa));              \
        float tf = fa; int ts = sa;                                    \
        if (sw) { fa = fb; sa = sb; fb = tf; sb = ts; }                \
    } while (0)

    CSWAP(s0f, s0s, s1f, s1s);
    CSWAP(s2f, s2s, s3f, s3s);
    CSWAP(s0f, s0s, s2f, s2s);
    CSWAP(s1f, s1s, s3f, s3s);
    CSWAP(s1f, s1s, s2f, s2s);
#undef CSWAP

    float wts[5] = { 1.0f - s0f, s0f - s1f, s1f - s2f, s2f - s3f, s3f };
    int flats[5];
    flats[0] = ((b0 * DD + b1) * DD + b2) * DD + b3;
    flats[1] = flats[0] + s0s;
    flats[2] = flats[1] + s1s;
    flats[3] = flats[2] + s2s;
    flats[4] = flats[3] + s3s;

    float acc[SS];
#pragma unroll
    for (int i = 0; i < SS; ++i) acc[i] = 0.0f;

    const float* wb = weight + b * (NL * HWPX) + hw;

#pragma unroll
    for (int l = 0; l < NL; ++l) {
        float wlv = wb[l * HWPX];
        const float* lbase = lut + (size_t)l * D4 * SS;
#pragma unroll
        for (int k = 0; k < 5; ++k) {
            float c = wlv * wts[k];
            const float4* row = (const float4*)(lbase + (size_t)flats[k] * SS);
#pragma unroll
            for (int q = 0; q < 4; ++q) {
                float4 rr = row[q];
                acc[q * 4 + 0] = fmaf(c, rr.x, acc[q * 4 + 0]);
                acc[q * 4 + 1] = fmaf(c, rr.y, acc[q * 4 + 1]);
                acc[q * 4 + 2] = fmaf(c, rr.z, acc[q * 4 + 2]);
                acc[q * 4 + 3] = fmaf(c, rr.w, acc[q * 4 + 3]);
            }
        }
    }

    float* ob = out + (size_t)b * (HH * 4) * (WW * 4) + (size_t)(h * 4) * (WW * 4) + (w * 4);
#pragma unroll
    for (int i = 0; i < 4; ++i) {
        *((float4*)(ob + (size_t)i * (WW * 4))) =
            make_float4(acc[i * 4 + 0], acc[i * 4 + 1], acc[i * 4 + 2], acc[i * 4 + 3]);
    }
}

extern "C" void kernel_launch(void* const* d_in, const int* in_sizes, int n_in,
                              void* d_out, int out_size, void* d_ws, size_t ws_size,
                              hipStream_t stream) {
    const float* lut    = (const float*)d_in[0];
    // d_in[1] = tri_index (unused by the reference computation)
    const float* weight = (const float*)d_in[2];
    const float* x      = (const float*)d_in[3];
    float* out          = (float*)d_out;

    dim3 block(256);

    if (ws_size >= LUT_BYTES_H) {
        ushort* lutT = (ushort*)d_ws;
        int n_chunks = D4 * NL * 4;                   // 1,336,336 4-half chunks
        dim3 grid_t((n_chunks + 255) / 256);
        hipLaunchKernelGGL(lut_transpose_h_kernel, grid_t, block, 0, stream,
                           (const float4*)lut, lutT);
        // Prewarm: every XCD streams the same 3.5MiB lutT window into its L2
        // as clean lines (8 replicas per chunk, stride 897 coprime to 8).
        hipLaunchKernelGGL(lut_touch_kernel, dim3(8 * TOUCH_STRIDE), block, 0,
                           stream, (const uint4*)lutT);
        dim3 grid_main(8192);   // 8 * 262144 threads / 256
        hipLaunchKernelGGL(lut4d_kernel_v, grid_main, block, 0, stream,
                           lutT, weight, x, out);
    } else {
        dim3 grid_main(1024);
        hipLaunchKernelGGL(lut4d_kernel_fallback, grid_main, block, 0, stream,
                           lut, weight, x, out);
    }
}

// Round 9
// 101.608 us; speedup vs baseline: 1.0306x; 1.0306x over previous
//
#include <hip/hip_runtime.h>
#include <hip/hip_fp16.h>

// Problem constants: L=4, DIM=17, S=4, B=4, H=256, W=256, BINSIZE=16
#define HH   256
#define WW   256
#define HWPX (HH * WW)           // 65536
#define DD   17
#define D4   (17 * 17 * 17 * 17) // 83521
#define NL   4
#define SS   16                  // S*S
#define LUT_FLOATS  (NL * D4 * SS)            // 5,345,344 floats
#define LUT_BYTES_H ((size_t)LUT_FLOATS * 2)  // ~10.7 MB (fp16 transposed copy)
#define LUT_UINT4   (LUT_BYTES_H / 16)        // 668,168 uint4 elements

// ---------------------------------------------------------------------------
// Kernel 1: transpose + fp16-convert LUT (L, D4, 16) f32 -> (D4, L, 16) f16.
// One vertex's four l-rows become exactly ONE 128B cache line.
// ---------------------------------------------------------------------------
__global__ __launch_bounds__(256) void lut_transpose_h_kernel(
    const float4* __restrict__ src,   // (L, D4, 4) float4
    ushort* __restrict__ dst)         // (D4, L, 16) halfs as ushort
{
    int t = blockIdx.x * blockDim.x + threadIdx.x;  // 4-half chunk index in dst
    if (t >= D4 * NL * 4) return;
    int c4 = t & 3;
    int l  = (t >> 2) & 3;
    int v  = t >> 4;
    float4 r = src[(size_t)l * (D4 * 4) + (size_t)v * 4 + c4];
    ushort4 h;
    h.x = __half_as_ushort(__float2half_rn(r.x));
    h.y = __half_as_ushort(__float2half_rn(r.y));
    h.z = __half_as_ushort(__float2half_rn(r.z));
    h.w = __half_as_ushort(__float2half_rn(r.w));
    *((ushort4*)(dst + (size_t)t * 4)) = h;   // coalesced 8B stores
}

// ---------------------------------------------------------------------------
// Kernel 1.5 (FINAL prewarm falsification): single full sweep of lutT
// (10.7 MB, read once, coalesced). Populates the SHARED 256MB L3 with 100%
// of the LUT before main — no XCD-mapping assumptions, no replication.
// Cost ~2us. If this is neutral, cross-kernel cache retention is dead and
// the chain is at its structural floor.
// ---------------------------------------------------------------------------
__global__ __launch_bounds__(256) void lut_touch_all_kernel(
    const uint4* __restrict__ lutT4)
{
    size_t i = (size_t)blockIdx.x * blockDim.x + threadIdx.x;
    if (i >= LUT_UINT4) return;
    uint4 v = lutT4[i];
    // keep the load alive without any memory side effect (rule #17)
    asm volatile("" :: "v"(v.x), "v"(v.y), "v"(v.z), "v"(v.w));
}

// ---------------------------------------------------------------------------
// Kernel 2: main interpolation (round-3 structure). 8 lanes per pixel;
// lane j does ONE dwordx4 (16B) load per vertex at flat*128 + j*16 -> the
// 8 lanes tile the whole 128B vertex line in a single instruction.
// 5 line-lookups per pixel; butterfly shfl_xor reduce over the 4 l-lanes.
// ---------------------------------------------------------------------------
__global__ __launch_bounds__(256) void lut4d_kernel_v(
    const ushort* __restrict__ lutT,   // (D4, L, 16) fp16
    const float* __restrict__ weight,  // (B, L, H, W)
    const float* __restrict__ x,       // (B, 1, H, W)
    float* __restrict__ out)           // (B, 1, H*4, W*4)
{
    int tid = blockIdx.x * blockDim.x + threadIdx.x;  // [0, 8*B*H*W)
    int j = tid & 7;          // sub-pixel lane: l = j>>1, half = j&1
    int p = tid >> 3;         // pixel id
    int b  = p >> 16;
    int hw = p & 65535;
    int h  = hw >> 8;
    int w  = hw & 255;
    int l  = j >> 1;

    const float* xb = x + b * HWPX;
    int h1 = (h + 1 < HH) ? (h + 1) : (HH - 2);   // reflect pad
    int w1 = (w + 1 < WW) ? (w + 1) : (WW - 2);

    float pix0 = xb[h  * WW + w ];
    float pix1 = xb[h  * WW + w1];
    float pix2 = xb[h1 * WW + w ];
    float pix3 = xb[h1 * WW + w1];

    // this lane's lut weight (only l = j>>1 needed per lane)
    float wlv = weight[(size_t)b * (NL * HWPX) + (size_t)l * HWPX + hw];

    const float inv = 1.0f / 16.0f;
    float t0 = pix0 * inv, t1 = pix1 * inv, t2 = pix2 * inv, t3 = pix3 * inv;
    float bf0 = floorf(t0), bf1 = floorf(t1), bf2 = floorf(t2), bf3 = floorf(t3);
    float f0 = t0 - bf0, f1 = t1 - bf1, f2 = t2 - bf2, f3 = t3 - bf3;

    int b0 = min(max((int)bf0, 0), DD - 2);
    int b1 = min(max((int)bf1, 0), DD - 2);
    int b2 = min(max((int)bf2, 0), DD - 2);
    int b3 = min(max((int)bf3, 0), DD - 2);

    // Stable descending sort of (frac, stride); strides strictly decrease
    // with original index so tie-break by larger stride == stable argsort.
    float s0f = f0, s1f = f1, s2f = f2, s3f = f3;
    int   s0s = 4913, s1s = 289, s2s = 17, s3s = 1;

#define CSWAP(fa, sa, fb, sb)                                          \
    do {                                                               \
        bool sw = (fb > fa) || ((fb == fa) && (sb > sa));              \
        float tf = fa; int ts = sa;                                    \
        if (sw) { fa = fb; sa = sb; fb = tf; sb = ts; }                \
    } while (0)

    CSWAP(s0f, s0s, s1f, s1s);
    CSWAP(s2f, s2s, s3f, s3s);
    CSWAP(s0f, s0s, s2f, s2s);
    CSWAP(s1f, s1s, s3f, s3s);
    CSWAP(s1f, s1s, s2f, s2s);
#undef CSWAP

    float wts[5];
    wts[0] = 1.0f - s0f;
    wts[1] = s0f - s1f;
    wts[2] = s1f - s2f;
    wts[3] = s2f - s3f;
    wts[4] = s3f;

    int flats[5];
    flats[0] = ((b0 * DD + b1) * DD + b2) * DD + b3;
    flats[1] = flats[0] + s0s;
    flats[2] = flats[1] + s1s;
    flats[3] = flats[2] + s2s;
    flats[4] = flats[3] + s3s;

    // Issue all 5 independent 16B gathers: lane j covers bytes [j*16, j*16+16)
    // of the 128B vertex line -> one fully-coalesced line fetch per vertex.
    uint4 r[5];
#pragma unroll
    for (int k = 0; k < 5; ++k) {
        const ushort* vbase = lutT + (size_t)flats[k] * (NL * SS);
        r[k] = *((const uint4*)(vbase) + j);
    }

    // Lane j holds lut[l = j>>1][channels (j&1)*8 .. +7] for each vertex.
    float acc0 = 0.f, acc1 = 0.f, acc2 = 0.f, acc3 = 0.f;
    float acc4 = 0.f, acc5 = 0.f, acc6 = 0.f, acc7 = 0.f;
#pragma unroll
    for (int k = 0; k < 5; ++k) {
        float c = wlv * wts[k];
        float2 f0v = __half22float2(*reinterpret_cast<const __half2*>(&r[k].x));
        float2 f1v = __half22float2(*reinterpret_cast<const __half2*>(&r[k].y));
        float2 f2v = __half22float2(*reinterpret_cast<const __half2*>(&r[k].z));
        float2 f3v = __half22float2(*reinterpret_cast<const __half2*>(&r[k].w));
        acc0 = fmaf(c, f0v.x, acc0);
        acc1 = fmaf(c, f0v.y, acc1);
        acc2 = fmaf(c, f1v.x, acc2);
        acc3 = fmaf(c, f1v.y, acc3);
        acc4 = fmaf(c, f2v.x, acc4);
        acc5 = fmaf(c, f2v.y, acc5);
        acc6 = fmaf(c, f3v.x, acc6);
        acc7 = fmaf(c, f3v.y, acc7);
    }

    // Butterfly-sum across the 4 l-lanes (same j&1): masks 2 then 4.
#define RED(mask)                                                      \
    do {                                                               \
        acc0 += __shfl_xor(acc0, mask, 64);                            \
        acc1 += __shfl_xor(acc1, mask, 64);                            \
        acc2 += __shfl_xor(acc2, mask, 64);                            \
        acc3 += __shfl_xor(acc3, mask, 64);                            \
        acc4 += __shfl_xor(acc4, mask, 64);                            \
        acc5 += __shfl_xor(acc5, mask, 64);                            \
        acc6 += __shfl_xor(acc6, mask, 64);                            \
        acc7 += __shfl_xor(acc7, mask, 64);                            \
    } while (0)
    RED(2);
    RED(4);
#undef RED

    // All 4 l-lanes now hold identical sums for channels (j&1)*8 .. +7.
    // Lane j writes global channels c0 = (j&1)*8 + (j>>1)*2, c0+1.
    int sel = j >> 1;
    float o0 = (sel == 0) ? acc0 : (sel == 1) ? acc2 : (sel == 2) ? acc4 : acc6;
    float o1 = (sel == 0) ? acc1 : (sel == 1) ? acc3 : (sel == 2) ? acc5 : acc7;

    int c0  = (j & 1) * 8 + sel * 2;
    int row = c0 >> 2;        // s-row
    int col = c0 & 3;         // s-col
    float* ob = out + (size_t)b * (HH * 4) * (WW * 4)
                    + (size_t)(h * 4 + row) * (WW * 4)
                    + (w * 4) + col;
    *((float2*)ob) = make_float2(o0, o1);
}

// ---------------------------------------------------------------------------
// Fallback (no workspace): original layout, fp32.
// ---------------------------------------------------------------------------
__global__ __launch_bounds__(256) void lut4d_kernel_fallback(
    const float* __restrict__ lut,
    const float* __restrict__ weight,
    const float* __restrict__ x,
    float* __restrict__ out)
{
    int p = blockIdx.x * blockDim.x + threadIdx.x;
    int b  = p >> 16;
    int hw = p & 65535;
    int h  = hw >> 8;
    int w  = hw & 255;

    const float* xb = x + b * HWPX;
    int h1 = (h + 1 < HH) ? (h + 1) : (HH - 2);
    int w1 = (w + 1 < WW) ? (w + 1) : (WW - 2);

    float pix0 = xb[h  * WW + w ];
    float pix1 = xb[h  * WW + w1];
    float pix2 = xb[h1 * WW + w ];
    float pix3 = xb[h1 * WW + w1];

    const float inv = 1.0f / 16.0f;
    float t0 = pix0 * inv, t1 = pix1 * inv, t2 = pix2 * inv, t3 = pix3 * inv;
    float bf0 = floorf(t0), bf1 = floorf(t1), bf2 = floorf(t2), bf3 = floorf(t3);
    float f0 = t0 - bf0, f1 = t1 - bf1, f2 = t2 - bf2, f3 = t3 - bf3;

    int b0 = min(max((int)bf0, 0), DD - 2);
    int b1 = min(max((int)bf1, 0), DD - 2);
    int b2 = min(max((int)bf2, 0), DD - 2);
    int b3 = min(max((int)bf3, 0), DD - 2);

    float s0f = f0, s1f = f1, s2f = f2, s3f = f3;
    int   s0s = 4913, s1s = 289, s2s = 17, s3s = 1;

#define CSWAP(fa, sa, fb, sb)                                          \
    do {                                                               \
        bool sw = (fb > fa) || ((fb == fa) && (sb > sa));              \
        float tf = fa; int ts = sa;                                    \
        if (sw) { fa = fb; sa = sb; fb = tf; sb = ts; }                \
    } while (0)

    CSWAP(s0f, s0s, s1f, s1s);
    CSWAP(s2f, s2s, s3f, s3s);
    CSWAP(s0f, s0s, s2f, s2s);
    CSWAP(s1f, s1s, s3f, s3s);
    CSWAP(s1f, s1s, s2f, s2s);
#undef CSWAP

    float wts[5] = { 1.0f - s0f, s0f - s1f, s1f - s2f, s2f - s3f, s3f };
    int flats[5];
    flats[0] = ((b0 * DD + b1) * DD + b2) * DD + b3;
    flats[1] = flats[0] + s0s;
    flats[2] = flats[1] + s1s;
    flats[3] = flats[2] + s2s;
    flats[4] = flats[3] + s3s;

    float acc[SS];
#pragma unroll
    for (int i = 0; i < SS; ++i) acc[i] = 0.0f;

    const float* wb = weight + b * (NL * HWPX) + hw;

#pragma unroll
    for (int l = 0; l < NL; ++l) {
        float wlv = wb[l * HWPX];
        const float* lbase = lut + (size_t)l * D4 * SS;
#pragma unroll
        for (int k = 0; k < 5; ++k) {
            float c = wlv * wts[k];
            const float4* row = (const float4*)(lbase + (size_t)flats[k] * SS);
#pragma unroll
            for (int q = 0; q < 4; ++q) {
                float4 rr = row[q];
                acc[q * 4 + 0] = fmaf(c, rr.x, acc[q * 4 + 0]);
                acc[q * 4 + 1] = fmaf(c, rr.y, acc[q * 4 + 1]);
                acc[q * 4 + 2] = fmaf(c, rr.z, acc[q * 4 + 2]);
                acc[q * 4 + 3] = fmaf(c, rr.w, acc[q * 4 + 3]);
            }
        }
    }

    float* ob = out + (size_t)b * (HH * 4) * (WW * 4) + (size_t)(h * 4) * (WW * 4) + (w * 4);
#pragma unroll
    for (int i = 0; i < 4; ++i) {
        *((float4*)(ob + (size_t)i * (WW * 4))) =
            make_float4(acc[i * 4 + 0], acc[i * 4 + 1], acc[i * 4 + 2], acc[i * 4 + 3]);
    }
}

extern "C" void kernel_launch(void* const* d_in, const int* in_sizes, int n_in,
                              void* d_out, int out_size, void* d_ws, size_t ws_size,
                              hipStream_t stream) {
    const float* lut    = (const float*)d_in[0];
    // d_in[1] = tri_index (unused by the reference computation)
    const float* weight = (const float*)d_in[2];
    const float* x      = (const float*)d_in[3];
    float* out          = (float*)d_out;

    dim3 block(256);

    if (ws_size >= LUT_BYTES_H) {
        ushort* lutT = (ushort*)d_ws;
        int n_chunks = D4 * NL * 4;                   // 1,336,336 4-half chunks
        dim3 grid_t((n_chunks + 255) / 256);
        hipLaunchKernelGGL(lut_transpose_h_kernel, grid_t, block, 0, stream,
                           (const float4*)lut, lutT);
        // Full-LUT L3 prewarm: one coalesced sweep of all 10.7MB (~2us).
        dim3 grid_w((unsigned)((LUT_UINT4 + 255) / 256));
        hipLaunchKernelGGL(lut_touch_all_kernel, grid_w, block, 0, stream,
                           (const uint4*)lutT);
        dim3 grid_main(8192);   // 8 * 262144 threads / 256
        hipLaunchKernelGGL(lut4d_kernel_v, grid_main, block, 0, stream,
                           lutT, weight, x, out);
    } else {
        dim3 grid_main(1024);
        hipLaunchKernelGGL(lut4d_kernel_fallback, grid_main, block, 0, stream,
                           lut, weight, x, out);
    }
}

// Round 10
// 100.396 us; speedup vs baseline: 1.0430x; 1.0121x over previous
//
#include <hip/hip_runtime.h>
#include <hip/hip_fp16.h>

// Problem constants: L=4, DIM=17, S=4, B=4, H=256, W=256, BINSIZE=16
#define HH   256
#define WW   256
#define HWPX (HH * WW)           // 65536
#define DD   17
#define D4   (17 * 17 * 17 * 17) // 83521
#define NL   4
#define SS   16                  // S*S
#define LUT_FLOATS  (NL * D4 * SS)            // 5,345,344 floats
#define LUT_BYTES_H ((size_t)LUT_FLOATS * 2)  // ~10.7 MB (fp16 transposed copy)

// ---------------------------------------------------------------------------
// Kernel 1: transpose + fp16-convert LUT (L, D4, 16) f32 -> (D4, L, 16) f16.
// One vertex's four l-rows become exactly ONE 128B cache line.
// ---------------------------------------------------------------------------
__global__ __launch_bounds__(256) void lut_transpose_h_kernel(
    const float4* __restrict__ src,   // (L, D4, 4) float4
    ushort* __restrict__ dst)         // (D4, L, 16) halfs as ushort
{
    int t = blockIdx.x * blockDim.x + threadIdx.x;  // 4-half chunk index in dst
    if (t >= D4 * NL * 4) return;
    int c4 = t & 3;
    int l  = (t >> 2) & 3;
    int v  = t >> 4;
    float4 r = src[(size_t)l * (D4 * 4) + (size_t)v * 4 + c4];
    ushort4 h;
    h.x = __half_as_ushort(__float2half_rn(r.x));
    h.y = __half_as_ushort(__float2half_rn(r.y));
    h.z = __half_as_ushort(__float2half_rn(r.z));
    h.w = __half_as_ushort(__float2half_rn(r.w));
    *((ushort4*)(dst + (size_t)t * 4)) = h;   // coalesced 8B stores
}

// ---------------------------------------------------------------------------
// Kernel 2: main interpolation (round-3 structure; best measured, 99.2us e2e).
// 8 lanes per pixel; lane j does ONE dwordx4 (16B) load per vertex at
// flat*128 + j*16 -> the 8 lanes tile the whole 128B vertex line in a single
// instruction; 5 line-lookups per pixel. Butterfly shfl_xor reduce over the
// 4 l-lanes. HBM random-line latency-bound (all cheaper alternatives refuted
// in rounds 1-9; see session journal).
// ---------------------------------------------------------------------------
__global__ __launch_bounds__(256) void lut4d_kernel_v(
    const ushort* __restrict__ lutT,   // (D4, L, 16) fp16
    const float* __restrict__ weight,  // (B, L, H, W)
    const float* __restrict__ x,       // (B, 1, H, W)
    float* __restrict__ out)           // (B, 1, H*4, W*4)
{
    int tid = blockIdx.x * blockDim.x + threadIdx.x;  // [0, 8*B*H*W)
    int j = tid & 7;          // sub-pixel lane: l = j>>1, half = j&1
    int p = tid >> 3;         // pixel id
    int b  = p >> 16;
    int hw = p & 65535;
    int h  = hw >> 8;
    int w  = hw & 255;
    int l  = j >> 1;

    const float* xb = x + b * HWPX;
    int h1 = (h + 1 < HH) ? (h + 1) : (HH - 2);   // reflect pad
    int w1 = (w + 1 < WW) ? (w + 1) : (WW - 2);

    float pix0 = xb[h  * WW + w ];
    float pix1 = xb[h  * WW + w1];
    float pix2 = xb[h1 * WW + w ];
    float pix3 = xb[h1 * WW + w1];

    // this lane's lut weight (only l = j>>1 needed per lane)
    float wlv = weight[(size_t)b * (NL * HWPX) + (size_t)l * HWPX + hw];

    const float inv = 1.0f / 16.0f;
    float t0 = pix0 * inv, t1 = pix1 * inv, t2 = pix2 * inv, t3 = pix3 * inv;
    float bf0 = floorf(t0), bf1 = floorf(t1), bf2 = floorf(t2), bf3 = floorf(t3);
    float f0 = t0 - bf0, f1 = t1 - bf1, f2 = t2 - bf2, f3 = t3 - bf3;

    int b0 = min(max((int)bf0, 0), DD - 2);
    int b1 = min(max((int)bf1, 0), DD - 2);
    int b2 = min(max((int)bf2, 0), DD - 2);
    int b3 = min(max((int)bf3, 0), DD - 2);

    // Stable descending sort of (frac, stride); strides strictly decrease
    // with original index so tie-break by larger stride == stable argsort.
    float s0f = f0, s1f = f1, s2f = f2, s3f = f3;
    int   s0s = 4913, s1s = 289, s2s = 17, s3s = 1;

#define CSWAP(fa, sa, fb, sb)                                          \
    do {                                                               \
        bool sw = (fb > fa) || ((fb == fa) && (sb > sa));              \
        float tf = fa; int ts = sa;                                    \
        if (sw) { fa = fb; sa = sb; fb = tf; sb = ts; }                \
    } while (0)

    CSWAP(s0f, s0s, s1f, s1s);
    CSWAP(s2f, s2s, s3f, s3s);
    CSWAP(s0f, s0s, s2f, s2s);
    CSWAP(s1f, s1s, s3f, s3s);
    CSWAP(s1f, s1s, s2f, s2s);
#undef CSWAP

    float wts[5];
    wts[0] = 1.0f - s0f;
    wts[1] = s0f - s1f;
    wts[2] = s1f - s2f;
    wts[3] = s2f - s3f;
    wts[4] = s3f;

    int flats[5];
    flats[0] = ((b0 * DD + b1) * DD + b2) * DD + b3;
    flats[1] = flats[0] + s0s;
    flats[2] = flats[1] + s1s;
    flats[3] = flats[2] + s2s;
    flats[4] = flats[3] + s3s;

    // Issue all 5 independent 16B gathers: lane j covers bytes [j*16, j*16+16)
    // of the 128B vertex line -> one fully-coalesced line fetch per vertex.
    uint4 r[5];
#pragma unroll
    for (int k = 0; k < 5; ++k) {
        const ushort* vbase = lutT + (size_t)flats[k] * (NL * SS);
        r[k] = *((const uint4*)(vbase) + j);
    }

    // Lane j holds lut[l = j>>1][channels (j&1)*8 .. +7] for each vertex.
    float acc0 = 0.f, acc1 = 0.f, acc2 = 0.f, acc3 = 0.f;
    float acc4 = 0.f, acc5 = 0.f, acc6 = 0.f, acc7 = 0.f;
#pragma unroll
    for (int k = 0; k < 5; ++k) {
        float c = wlv * wts[k];
        float2 f0v = __half22float2(*reinterpret_cast<const __half2*>(&r[k].x));
        float2 f1v = __half22float2(*reinterpret_cast<const __half2*>(&r[k].y));
        float2 f2v = __half22float2(*reinterpret_cast<const __half2*>(&r[k].z));
        float2 f3v = __half22float2(*reinterpret_cast<const __half2*>(&r[k].w));
        acc0 = fmaf(c, f0v.x, acc0);
        acc1 = fmaf(c, f0v.y, acc1);
        acc2 = fmaf(c, f1v.x, acc2);
        acc3 = fmaf(c, f1v.y, acc3);
        acc4 = fmaf(c, f2v.x, acc4);
        acc5 = fmaf(c, f2v.y, acc5);
        acc6 = fmaf(c, f3v.x, acc6);
        acc7 = fmaf(c, f3v.y, acc7);
    }

    // Butterfly-sum across the 4 l-lanes (same j&1): masks 2 then 4.
#define RED(mask)                                                      \
    do {                                                               \
        acc0 += __shfl_xor(acc0, mask, 64);                            \
        acc1 += __shfl_xor(acc1, mask, 64);                            \
        acc2 += __shfl_xor(acc2, mask, 64);                            \
        acc3 += __shfl_xor(acc3, mask, 64);                            \
        acc4 += __shfl_xor(acc4, mask, 64);                            \
        acc5 += __shfl_xor(acc5, mask, 64);                            \
        acc6 += __shfl_xor(acc6, mask, 64);                            \
        acc7 += __shfl_xor(acc7, mask, 64);                            \
    } while (0)
    RED(2);
    RED(4);
#undef RED

    // All 4 l-lanes now hold identical sums for channels (j&1)*8 .. +7.
    // Lane j writes global channels c0 = (j&1)*8 + (j>>1)*2, c0+1.
    int sel = j >> 1;
    float o0 = (sel == 0) ? acc0 : (sel == 1) ? acc2 : (sel == 2) ? acc4 : acc6;
    float o1 = (sel == 0) ? acc1 : (sel == 1) ? acc3 : (sel == 2) ? acc5 : acc7;

    int c0  = (j & 1) * 8 + sel * 2;
    int row = c0 >> 2;        // s-row
    int col = c0 & 3;         // s-col
    float* ob = out + (size_t)b * (HH * 4) * (WW * 4)
                    + (size_t)(h * 4 + row) * (WW * 4)
                    + (w * 4) + col;
    *((float2*)ob) = make_float2(o0, o1);
}

// ---------------------------------------------------------------------------
// Fallback (no workspace): original layout, fp32.
// ---------------------------------------------------------------------------
__global__ __launch_bounds__(256) void lut4d_kernel_fallback(
    const float* __restrict__ lut,
    const float* __restrict__ weight,
    const float* __restrict__ x,
    float* __restrict__ out)
{
    int p = blockIdx.x * blockDim.x + threadIdx.x;
    int b  = p >> 16;
    int hw = p & 65535;
    int h  = hw >> 8;
    int w  = hw & 255;

    const float* xb = x + b * HWPX;
    int h1 = (h + 1 < HH) ? (h + 1) : (HH - 2);
    int w1 = (w + 1 < WW) ? (w + 1) : (WW - 2);

    float pix0 = xb[h  * WW + w ];
    float pix1 = xb[h  * WW + w1];
    float pix2 = xb[h1 * WW + w ];
    float pix3 = xb[h1 * WW + w1];

    const float inv = 1.0f / 16.0f;
    float t0 = pix0 * inv, t1 = pix1 * inv, t2 = pix2 * inv, t3 = pix3 * inv;
    float bf0 = floorf(t0), bf1 = floorf(t1), bf2 = floorf(t2), bf3 = floorf(t3);
    float f0 = t0 - bf0, f1 = t1 - bf1, f2 = t2 - bf2, f3 = t3 - bf3;

    int b0 = min(max((int)bf0, 0), DD - 2);
    int b1 = min(max((int)bf1, 0), DD - 2);
    int b2 = min(max((int)bf2, 0), DD - 2);
    int b3 = min(max((int)bf3, 0), DD - 2);

    float s0f = f0, s1f = f1, s2f = f2, s3f = f3;
    int   s0s = 4913, s1s = 289, s2s = 17, s3s = 1;

#define CSWAP(fa, sa, fb, sb)                                          \
    do {                                                               \
        bool sw = (fb > fa) || ((fb == fa) && (sb > sa));              \
        float tf = fa; int ts = sa;                                    \
        if (sw) { fa = fb; sa = sb; fb = tf; sb = ts; }                \
    } while (0)

    CSWAP(s0f, s0s, s1f, s1s);
    CSWAP(s2f, s2s, s3f, s3s);
    CSWAP(s0f, s0s, s2f, s2s);
    CSWAP(s1f, s1s, s3f, s3s);
    CSWAP(s1f, s1s, s2f, s2s);
#undef CSWAP

    float wts[5] = { 1.0f - s0f, s0f - s1f, s1f - s2f, s2f - s3f, s3f };
    int flats[5];
    flats[0] = ((b0 * DD + b1) * DD + b2) * DD + b3;
    flats[1] = flats[0] + s0s;
    flats[2] = flats[1] + s1s;
    flats[3] = flats[2] + s2s;
    flats[4] = flats[3] + s3s;

    float acc[SS];
#pragma unroll
    for (int i = 0; i < SS; ++i) acc[i] = 0.0f;

    const float* wb = weight + b * (NL * HWPX) + hw;

#pragma unroll
    for (int l = 0; l < NL; ++l) {
        float wlv = wb[l * HWPX];
        const float* lbase = lut + (size_t)l * D4 * SS;
#pragma unroll
        for (int k = 0; k < 5; ++k) {
            float c = wlv * wts[k];
            const float4* row = (const float4*)(lbase + (size_t)flats[k] * SS);
#pragma unroll
            for (int q = 0; q < 4; ++q) {
                float4 rr = row[q];
                acc[q * 4 + 0] = fmaf(c, rr.x, acc[q * 4 + 0]);
                acc[q * 4 + 1] = fmaf(c, rr.y, acc[q * 4 + 1]);
                acc[q * 4 + 2] = fmaf(c, rr.z, acc[q * 4 + 2]);
                acc[q * 4 + 3] = fmaf(c, rr.w, acc[q * 4 + 3]);
            }
        }
    }

    float* ob = out + (size_t)b * (HH * 4) * (WW * 4) + (size_t)(h * 4) * (WW * 4) + (w * 4);
#pragma unroll
    for (int i = 0; i < 4; ++i) {
        *((float4*)(ob + (size_t)i * (WW * 4))) =
            make_float4(acc[i * 4 + 0], acc[i * 4 + 1], acc[i * 4 + 2], acc[i * 4 + 3]);
    }
}

extern "C" void kernel_launch(void* const* d_in, const int* in_sizes, int n_in,
                              void* d_out, int out_size, void* d_ws, size_t ws_size,
                              hipStream_t stream) {
    const float* lut    = (const float*)d_in[0];
    // d_in[1] = tri_index (unused by the reference computation)
    const float* weight = (const float*)d_in[2];
    const float* x      = (const float*)d_in[3];
    float* out          = (float*)d_out;

    dim3 block(256);

    if (ws_size >= LUT_BYTES_H) {
        ushort* lutT = (ushort*)d_ws;
        int n_chunks = D4 * NL * 4;                   // 1,336,336 4-half chunks
        dim3 grid_t((n_chunks + 255) / 256);
        hipLaunchKernelGGL(lut_transpose_h_kernel, grid_t, block, 0, stream,
                           (const float4*)lut, lutT);
        dim3 grid_main(8192);   // 8 * 262144 threads / 256
        hipLaunchKernelGGL(lut4d_kernel_v, grid_main, block, 0, stream,
                           lutT, weight, x, out);
    } else {
        dim3 grid_main(1024);
        hipLaunchKernelGGL(lut4d_kernel_fallback, grid_main, block, 0, stream,
                           lut, weight, x, out);
    }
}